// Round 18
// baseline (120.681 us; speedup 1.0000x reference)
//
#include <hip/hip_runtime.h>

#define T_LEN 4096
#define D_IN 128
#define U_H 256
#define REC_MAXV 0.0625f

typedef __attribute__((ext_vector_type(4))) float f32x4;
typedef __attribute__((ext_vector_type(16))) float f32x16;
typedef __attribute__((ext_vector_type(2))) int int2v;
typedef long long i64;

template <bool HI>
__device__ __forceinline__ int pk8(float a, float b, int old) {
    return __builtin_amdgcn_cvt_pk_fp8_f32(a, b, old, HI);
}

__device__ __forceinline__ int reord32(int u) {
    int r = u & 31;
    return ((u >> 5) << 5) + (((r >> 2) & 1) << 4) + ((r >> 3) << 2) + (r & 3);
}

// ---------------- SINGLE kernel: per-block prep -> main -> last-block final --
// 1024 blocks x 512 threads (8 waves), 1 tile (32 rows)/wave, b = bid>>4.
// PREP (per block, redundant but L2-cheap): h for batch b -> budL in LDS;
//   boL in LDS; fp8 weight frags packed DIRECTLY into LDS (no global WF8);
//   blocks with (bid&15)==0 add the t=0 loss term into lacc (threads<128).
// MAIN: R16 rolled ut-loop (I$-resident body), fp8 32x32x16 MFMA.
// FINAL: part[bid] store -> threadfence -> atomicAdd(cnt); last block (old==
//   1023) reduces all 1024 partials and plain-stores loss. cnt reset each
//   call via hipMemsetAsync (graph-capturable).
__global__ __launch_bounds__(512, 2) void k_main(
        const float* __restrict__ xs, const float* __restrict__ We,
        const float* __restrict__ be, const float* __restrict__ Wd,
        const float* __restrict__ bd, const float* __restrict__ ud,
        const float* __restrict__ Wo, const float* __restrict__ bo,
        float* __restrict__ part, int* __restrict__ cnt,
        float* __restrict__ loss) {
    __shared__ __align__(16) char lds[67200];
    const int tid = threadIdx.x;
    const int bid = blockIdx.x;
    const int b = bid >> 4;
    float* budL = (float*)(lds + 65536);   // 1 KB
    float* boL  = (float*)(lds + 66560);   // 512 B
    float* wsumf = (float*)(lds + 67072);  // 8 floats
    int*   lflag = (int*)(lds + 67104);

    float lacc = 0.f;

    // ================= PREP (in-block) =================
    {
        float* hL = (float*)lds;           // [0,1K) -- overwritten by packing later
        // ---- h[b][u] for u = tid < 256 ----
        if (tid < 256) {
            const f32x4* xr = (const f32x4*)(xs + ((size_t)b * T_LEN + (T_LEN - 1)) * D_IN);
            const f32x4* wr = (const f32x4*)(We + (size_t)tid * D_IN);
            float s = 0.f;
#pragma unroll
            for (int i = 0; i < 32; ++i) {
                f32x4 a = xr[i], w = wr[i];
                s += a[0]*w[0] + a[1]*w[1] + a[2]*w[2] + a[3]*w[3];
            }
            s += be[tid];
            s = fmaxf(s, 0.f);
            hL[tid] = s;
            float udc = fminf(fmaxf(ud[tid], -REC_MAXV), REC_MAXV);
            budL[reord32(tid)] = bd[tid] + udc * s;
        } else if (tid < 384) {
            boL[reord32(tid - 256)] = bo[tid - 256];
        }
        __syncthreads();

        // ---- t=0 loss term (only 1 block per batch; threads 0..127 = d) ----
        if ((bid & 15) == 0 && tid < 128) {
            const f32x4* hr = (const f32x4*)hL;
            const f32x4* wo = (const f32x4*)(Wo + (size_t)tid * U_H);
            float s2 = 0.f;
#pragma unroll
            for (int i = 0; i < 64; ++i) {
                f32x4 a = hr[i], w = wo[i];
                s2 += a[0]*w[0] + a[1]*w[1] + a[2]*w[2] + a[3]*w[3];
            }
            s2 += bo[tid];
            float x = xs[((size_t)b * T_LEN + T_LEN - 1) * D_IN + tid];
            float diff = x - s2;
            lacc += diff * diff;           // flows into the block reduction
        }
        __syncthreads();                   // hL reads done before packing

        // ---- fp8 weight frags packed directly into LDS ----
#pragma clang loop unroll(disable)
        for (int k = 0; k < 16; ++k) {
            int gid = tid + (k << 9);      // 0..8191
            if (gid < 4096) {
                int f = gid >> 6, l = gid & 63;
                int ut = f >> 3, ks = f & 7;
                const float* src = Wd + (size_t)(ut * 32 + (l & 31)) * D_IN + ks * 16 + (l >> 5) * 8;
                int lo = pk8<false>(src[0], src[1], 0); lo = pk8<true>(src[2], src[3], lo);
                int hh = pk8<false>(src[4], src[5], 0); hh = pk8<true>(src[6], src[7], hh);
                *(int2v*)(lds + (size_t)gid * 8) = (int2v){lo, hh};
            } else {
                int g = gid - 4096;
                int f = g >> 6, l = g & 63;
                int uk = f >> 2, dt = f & 3;
                const float* src = Wo + (size_t)(dt * 32 + (l & 31)) * U_H + uk * 16 + (l >> 5) * 8;
                int lo = pk8<false>(src[0], src[1], 0); lo = pk8<true>(src[2], src[3], lo);
                int hh = pk8<false>(src[4], src[5], 0); hh = pk8<true>(src[6], src[7], hh);
                *(int2v*)(lds + 32768 + (size_t)g * 8) = (int2v){lo, hh};
            }
        }
        __syncthreads();
    }

    // ================= MAIN (R16 rolled structure) =================
    const int wave = tid >> 6, lane = tid & 63;
    const int m = lane & 31, hi = lane >> 5;
    const float* xsb = xs + ((size_t)b << 19);

    const int tile = bid * 8 + wave;
    const int t0 = (tile & 127) << 5;

    // ---- X row -> fp8 B-frags (8 named i64) ----
    const float* xrow = xsb + (size_t)(t0 + m) * 128 + hi * 8;
    i64 x0, x1, x2, x3, x4, x5, x6, x7;
    {
#define LDX(KS, XV)                                                      \
        {   f32x4 v0 = *(const f32x4*)(xrow + KS * 16);                  \
            f32x4 v1 = *(const f32x4*)(xrow + KS * 16 + 4);              \
            int lo = pk8<false>(v0[0], v0[1], 0); lo = pk8<true>(v0[2], v0[3], lo); \
            int hh = pk8<false>(v1[0], v1[1], 0); hh = pk8<true>(v1[2], v1[3], hh); \
            XV = __builtin_bit_cast(i64, (int2v){lo, hh}); }
        LDX(0, x0) LDX(1, x1) LDX(2, x2) LDX(3, x3)
        LDX(4, x4) LDX(5, x5) LDX(6, x6) LDX(7, x7)
#undef LDX
    }

    // ---- o accumulators init from boL (bo folded into GEMM2 C-init) ----
    f32x16 o0, o1, o2, o3;
#define OINIT(OV, DT)                                                    \
    {   const float* bp = boL + (DT) * 32 + hi * 16;                     \
        f32x4 b0 = *(const f32x4*)(bp), b1 = *(const f32x4*)(bp + 4);    \
        f32x4 b2 = *(const f32x4*)(bp + 8), b3 = *(const f32x4*)(bp + 12); \
        OV[0]=b0[0]; OV[1]=b0[1]; OV[2]=b0[2]; OV[3]=b0[3];              \
        OV[4]=b1[0]; OV[5]=b1[1]; OV[6]=b1[2]; OV[7]=b1[3];              \
        OV[8]=b2[0]; OV[9]=b2[1]; OV[10]=b2[2]; OV[11]=b2[3];            \
        OV[12]=b3[0]; OV[13]=b3[1]; OV[14]=b3[2]; OV[15]=b3[3]; }
    OINIT(o0, 0) OINIT(o1, 1) OINIT(o2, 2) OINIT(o3, 3)
#undef OINIT

#pragma clang loop unroll(disable)
    for (int ut = 0; ut < 8; ++ut) {
        f32x16 ca, cb;
        {
            const float* bp = budL + ut * 32 + hi * 16;
            f32x4 b0 = *(const f32x4*)(bp), b1 = *(const f32x4*)(bp + 4);
            f32x4 b2 = *(const f32x4*)(bp + 8), b3 = *(const f32x4*)(bp + 12);
            ca[0]=b0[0]; ca[1]=b0[1]; ca[2]=b0[2]; ca[3]=b0[3];
            ca[4]=b1[0]; ca[5]=b1[1]; ca[6]=b1[2]; ca[7]=b1[3];
            ca[8]=b2[0]; ca[9]=b2[1]; ca[10]=b2[2]; ca[11]=b2[3];
            ca[12]=b3[0]; ca[13]=b3[1]; ca[14]=b3[2]; ca[15]=b3[3];
#pragma unroll
            for (int i = 0; i < 16; ++i) cb[i] = 0.f;
        }
        const char* wb = lds + ((ut * 8) << 9) + (lane << 3);
        ca = __builtin_amdgcn_mfma_f32_32x32x16_fp8_fp8(*(const i64*)(wb + 0*512), x0, ca, 0,0,0);
        cb = __builtin_amdgcn_mfma_f32_32x32x16_fp8_fp8(*(const i64*)(wb + 1*512), x1, cb, 0,0,0);
        ca = __builtin_amdgcn_mfma_f32_32x32x16_fp8_fp8(*(const i64*)(wb + 2*512), x2, ca, 0,0,0);
        cb = __builtin_amdgcn_mfma_f32_32x32x16_fp8_fp8(*(const i64*)(wb + 3*512), x3, cb, 0,0,0);
        ca = __builtin_amdgcn_mfma_f32_32x32x16_fp8_fp8(*(const i64*)(wb + 4*512), x4, ca, 0,0,0);
        cb = __builtin_amdgcn_mfma_f32_32x32x16_fp8_fp8(*(const i64*)(wb + 5*512), x5, cb, 0,0,0);
        ca = __builtin_amdgcn_mfma_f32_32x32x16_fp8_fp8(*(const i64*)(wb + 6*512), x6, ca, 0,0,0);
        cb = __builtin_amdgcn_mfma_f32_32x32x16_fp8_fp8(*(const i64*)(wb + 7*512), x7, cb, 0,0,0);

        i64 dlo, dhi;
        {
            f32x16 c;
#pragma unroll
            for (int i = 0; i < 16; ++i) c[i] = fmaxf(ca[i] + cb[i], 0.f);
            int d0 = pk8<false>(c[0],  c[1],  0); d0 = pk8<true>(c[2],  c[3],  d0);
            int d1 = pk8<false>(c[4],  c[5],  0); d1 = pk8<true>(c[6],  c[7],  d1);
            int d2 = pk8<false>(c[8],  c[9],  0); d2 = pk8<true>(c[10], c[11], d2);
            int d3 = pk8<false>(c[12], c[13], 0); d3 = pk8<true>(c[14], c[15], d3);
            int2v s = __builtin_amdgcn_permlane32_swap(d0, d1, false, false);
            int2v t = __builtin_amdgcn_permlane32_swap(d2, d3, false, false);
            dlo = __builtin_bit_cast(i64, s);
            dhi = __builtin_bit_cast(i64, t);
        }

        const char* w2 = lds + 32768 + ((ut * 8) << 9) + (lane << 3);
        o0 = __builtin_amdgcn_mfma_f32_32x32x16_fp8_fp8(*(const i64*)(w2 + 0*512), dlo, o0, 0,0,0);
        o1 = __builtin_amdgcn_mfma_f32_32x32x16_fp8_fp8(*(const i64*)(w2 + 1*512), dlo, o1, 0,0,0);
        o2 = __builtin_amdgcn_mfma_f32_32x32x16_fp8_fp8(*(const i64*)(w2 + 2*512), dlo, o2, 0,0,0);
        o3 = __builtin_amdgcn_mfma_f32_32x32x16_fp8_fp8(*(const i64*)(w2 + 3*512), dlo, o3, 0,0,0);
        o0 = __builtin_amdgcn_mfma_f32_32x32x16_fp8_fp8(*(const i64*)(w2 + 4*512), dhi, o0, 0,0,0);
        o1 = __builtin_amdgcn_mfma_f32_32x32x16_fp8_fp8(*(const i64*)(w2 + 5*512), dhi, o1, 0,0,0);
        o2 = __builtin_amdgcn_mfma_f32_32x32x16_fp8_fp8(*(const i64*)(w2 + 6*512), dhi, o2, 0,0,0);
        o3 = __builtin_amdgcn_mfma_f32_32x32x16_fp8_fp8(*(const i64*)(w2 + 7*512), dhi, o3, 0,0,0);
    }

    // ---- fused loss epilogue (bo already inside o) ----
    const int t = t0 + m;
    const float sel = (t > 0) ? 1.f : 0.f;
    const float* trow = xsb + (size_t)((t > 0) ? t - 1 : 0) * 128;
#define EPI(OV, DT)                                                      \
    {   _Pragma("unroll")                                                \
        for (int q = 0; q < 4; ++q) {                                    \
            f32x4 tg = *(const f32x4*)(trow + (DT) * 32 + q * 8 + hi * 4); \
            _Pragma("unroll")                                            \
            for (int j = 0; j < 4; ++j) {                                \
                float diff = tg[j] - OV[q * 4 + j];                      \
                lacc += sel * diff * diff;                               \
            }                                                            \
        }                                                                \
    }
    EPI(o0, 0) EPI(o1, 1) EPI(o2, 2) EPI(o3, 3)
#undef EPI

    // ================= block reduction + last-block final =================
#pragma unroll
    for (int o = 32; o > 0; o >>= 1) lacc += __shfl_down(lacc, o);
    if (lane == 0) wsumf[wave] = lacc;
    __syncthreads();
    if (tid == 0) {
        float s = 0.f;
#pragma unroll
        for (int i = 0; i < 8; ++i) s += wsumf[i];
        part[bid] = s;
        __threadfence();
        int old = atomicAdd(cnt, 1);
        lflag[0] = (old == 1023) ? 1 : 0;
    }
    __syncthreads();
    if (lflag[0]) {
        __threadfence();
        float v = part[tid] + part[tid + 512];
#pragma unroll
        for (int o = 32; o > 0; o >>= 1) v += __shfl_down(v, o);
        if (lane == 0) wsumf[wave] = v;
        __syncthreads();
        if (tid == 0) {
            float s = 0.f;
#pragma unroll
            for (int i = 0; i < 8; ++i) s += wsumf[i];
            *loss = s * (1.f / 262144.f);
        }
    }
}

extern "C" void kernel_launch(void* const* d_in, const int* in_sizes, int n_in,
                              void* d_out, int out_size, void* d_ws, size_t ws_size,
                              hipStream_t stream) {
    const float* xs = (const float*)d_in[0];
    const float* We = (const float*)d_in[1];
    const float* be = (const float*)d_in[2];
    // d_in[3] = ue (unused: encoder hidden state is always zero)
    const float* Wd = (const float*)d_in[4];
    const float* bd = (const float*)d_in[5];
    const float* ud = (const float*)d_in[6];
    const float* Wo = (const float*)d_in[7];
    const float* bo = (const float*)d_in[8];
    float* loss = (float*)d_out;

    char* wsb = (char*)d_ws;
    float* part = (float*)(wsb);            // 4096 B (1024 block partials)
    int*   cnt  = (int*)(wsb + 4096);       // 4 B completion counter

    hipMemsetAsync(cnt, 0, 4, stream);      // deterministic per-call reset
    k_main<<<1024, 512, 0, stream>>>(xs, We, be, Wd, bd, ud, Wo, bo,
                                     part, cnt, loss);
}

// Round 19
// 95.435 us; speedup vs baseline: 1.2645x; 1.2645x over previous
//
#include <hip/hip_runtime.h>

#define T_LEN 4096
#define D_IN 128
#define U_H 256
#define REC_MAXV 0.0625f

typedef __attribute__((ext_vector_type(4))) float f32x4;
typedef __attribute__((ext_vector_type(16))) float f32x16;
typedef __attribute__((ext_vector_type(2))) int int2v;
typedef long long i64;

template <bool HI>
__device__ __forceinline__ int pk8(float a, float b, int old) {
    return __builtin_amdgcn_cvt_pk_fp8_f32(a, b, old, HI);
}

__device__ __forceinline__ int reord32(int u) {
    int r = u & 31;
    return ((u >> 5) << 5) + (((r >> 2) & 1) << 4) + ((r >> 3) << 2) + (r & 3);
}

// -------- kernel 0 (fused prep): h, budR, boR, fp8 weight frags, loss0 -------
// (R16 version -- prep ONCE, amortized; R18 proved per-block prep is 2x worse)
__global__ void k_pre(const float* __restrict__ xs, const float* __restrict__ We,
                      const float* __restrict__ be, const float* __restrict__ Wd,
                      const float* __restrict__ bd, const float* __restrict__ ud,
                      const float* __restrict__ Wo, const float* __restrict__ bo,
                      float* __restrict__ budR, float* __restrict__ boR,
                      char* __restrict__ WF8, float* __restrict__ part2) {
    __shared__ __align__(16) float hL[256];
    __shared__ float red[2];
    const int b = blockIdx.x, u = threadIdx.x;

    const f32x4* xr = (const f32x4*)(xs + ((size_t)b * T_LEN + (T_LEN - 1)) * D_IN);
    const f32x4* wr = (const f32x4*)(We + (size_t)u * D_IN);
    float s = 0.f;
#pragma unroll
    for (int i = 0; i < 32; ++i) {
        f32x4 a = xr[i], w = wr[i];
        s += a[0]*w[0] + a[1]*w[1] + a[2]*w[2] + a[3]*w[3];
    }
    s += be[u];
    s = fmaxf(s, 0.f);
    hL[u] = s;

    float udc = fminf(fmaxf(ud[u], -REC_MAXV), REC_MAXV);
    budR[(b << 8) + reord32(u)] = bd[u] + udc * s;

    if (b == 0 && u < 128) boR[reord32(u)] = bo[u];

    int gid = b * 256 + u;
    if (gid < 4096) {
        int f = gid >> 6, l = gid & 63;
        int ut = f >> 3, ks = f & 7;
        const float* src = Wd + (size_t)(ut * 32 + (l & 31)) * D_IN + ks * 16 + (l >> 5) * 8;
        int lo = pk8<false>(src[0], src[1], 0); lo = pk8<true>(src[2], src[3], lo);
        int hh = pk8<false>(src[4], src[5], 0); hh = pk8<true>(src[6], src[7], hh);
        *(int2v*)(WF8 + (size_t)gid * 8) = (int2v){lo, hh};
    } else if (gid < 8192) {
        int g = gid - 4096;
        int f = g >> 6, l = g & 63;
        int uk = f >> 2, dt = f & 3;
        const float* src = Wo + (size_t)(dt * 32 + (l & 31)) * U_H + uk * 16 + (l >> 5) * 8;
        int lo = pk8<false>(src[0], src[1], 0); lo = pk8<true>(src[2], src[3], lo);
        int hh = pk8<false>(src[4], src[5], 0); hh = pk8<true>(src[6], src[7], hh);
        *(int2v*)(WF8 + 32768 + (size_t)g * 8) = (int2v){lo, hh};
    }
    __syncthreads();

    float v = 0.f;
    if (u < 128) {
        const f32x4* hr = (const f32x4*)hL;
        const f32x4* wo = (const f32x4*)(Wo + (size_t)u * U_H);
        float s2 = 0.f;
#pragma unroll
        for (int i = 0; i < 64; ++i) {
            f32x4 a = hr[i], w = wo[i];
            s2 += a[0]*w[0] + a[1]*w[1] + a[2]*w[2] + a[3]*w[3];
        }
        s2 += bo[u];
        float x = xs[((size_t)b * T_LEN + T_LEN - 1) * D_IN + u];
        float diff = x - s2;
        v = diff * diff;
    }
#pragma unroll
    for (int o = 32; o > 0; o >>= 1) v += __shfl_down(v, o);
    if (u == 0) red[0] = v;
    if (u == 64) red[1] = v;
    __syncthreads();
    if (u == 0) part2[b] = red[0] + red[1];
}

// ---------------- kernel 1: main (rolled loop) + last-block final ------------
// 1024 blocks x 512 threads (8 waves), 1 tile (32 rows)/wave.
// Changes vs R16: (a) X's 16 HBM loads ISSUED BEFORE the weight-staging loop
// (HBM latency hides under L2-hot staging; raw held in 16 named f32x4);
// (b) final reduction folded in via last-block-done pattern (R18-verified):
// saves the k_final launch + gap.
__global__ __launch_bounds__(512, 2) void k_main(
        const float* __restrict__ xs, const float* __restrict__ budR,
        const float* __restrict__ boR, const char* __restrict__ WF8,
        const float* __restrict__ part2, float* __restrict__ part,
        int* __restrict__ cnt, float* __restrict__ loss) {
    __shared__ __align__(16) char lds[67200];
    const int tid = threadIdx.x;
    const int bid = blockIdx.x;
    const int b = bid >> 4;          // 16 blocks per batch-entry
    float* wsumf = (float*)(lds + 67072);
    int*   lflag = (int*)(lds + 67104);

    const int wave = tid >> 6, lane = tid & 63;
    const int m = lane & 31, hi = lane >> 5;
    const float* xsb = xs + ((size_t)b << 19);
    const int tile = bid * 8 + wave;
    const int t0 = (tile & 127) << 5;

    // ---- (a) issue X loads FIRST (raw f32, 16 named f32x4) ----
    const float* xrow = xsb + (size_t)(t0 + m) * 128 + hi * 8;
    f32x4 r0  = *(const f32x4*)(xrow +   0), r1  = *(const f32x4*)(xrow +   4);
    f32x4 r2  = *(const f32x4*)(xrow +  16), r3  = *(const f32x4*)(xrow +  20);
    f32x4 r4  = *(const f32x4*)(xrow +  32), r5  = *(const f32x4*)(xrow +  36);
    f32x4 r6  = *(const f32x4*)(xrow +  48), r7  = *(const f32x4*)(xrow +  52);
    f32x4 r8  = *(const f32x4*)(xrow +  64), r9  = *(const f32x4*)(xrow +  68);
    f32x4 r10 = *(const f32x4*)(xrow +  80), r11 = *(const f32x4*)(xrow +  84);
    f32x4 r12 = *(const f32x4*)(xrow +  96), r13 = *(const f32x4*)(xrow + 100);
    f32x4 r14 = *(const f32x4*)(xrow + 112), r15 = *(const f32x4*)(xrow + 116);

    // ---- weight/bias staging (L2-hot; overlaps the X HBM latency) ----
    for (int i = tid; i < 4096; i += 512)
        ((f32x4*)lds)[i] = ((const f32x4*)WF8)[i];
    if (tid < 64) ((f32x4*)(lds + 65536))[tid] = ((const f32x4*)(budR + b * 256))[tid];
    else if (tid < 96) ((f32x4*)(lds + 66560))[tid - 64] = ((const f32x4*)boR)[tid - 64];
    __syncthreads();

    const float* budL = (const float*)(lds + 65536);
    const float* boL  = (const float*)(lds + 66560);

    // ---- convert raw X -> fp8 B-frags (frees the 64 raw regs) ----
    i64 x0, x1, x2, x3, x4, x5, x6, x7;
#define CV(V0, V1, XV)                                                   \
    {   int lo = pk8<false>(V0[0], V0[1], 0); lo = pk8<true>(V0[2], V0[3], lo); \
        int hh = pk8<false>(V1[0], V1[1], 0); hh = pk8<true>(V1[2], V1[3], hh); \
        XV = __builtin_bit_cast(i64, (int2v){lo, hh}); }
    CV(r0,  r1,  x0) CV(r2,  r3,  x1) CV(r4,  r5,  x2) CV(r6,  r7,  x3)
    CV(r8,  r9,  x4) CV(r10, r11, x5) CV(r12, r13, x6) CV(r14, r15, x7)
#undef CV

    // ---- o accumulators init from boL (bo folded into GEMM2 C-init) ----
    f32x16 o0, o1, o2, o3;
#define OINIT(OV, DT)                                                    \
    {   const float* bp = boL + (DT) * 32 + hi * 16;                     \
        f32x4 b0 = *(const f32x4*)(bp), b1 = *(const f32x4*)(bp + 4);    \
        f32x4 b2 = *(const f32x4*)(bp + 8), b3 = *(const f32x4*)(bp + 12); \
        OV[0]=b0[0]; OV[1]=b0[1]; OV[2]=b0[2]; OV[3]=b0[3];              \
        OV[4]=b1[0]; OV[5]=b1[1]; OV[6]=b1[2]; OV[7]=b1[3];              \
        OV[8]=b2[0]; OV[9]=b2[1]; OV[10]=b2[2]; OV[11]=b2[3];            \
        OV[12]=b3[0]; OV[13]=b3[1]; OV[14]=b3[2]; OV[15]=b3[3]; }
    OINIT(o0, 0) OINIT(o1, 1) OINIT(o2, 2) OINIT(o3, 3)
#undef OINIT

    // ---- main rolled loop over ut (I$-resident body) ----
#pragma clang loop unroll(disable)
    for (int ut = 0; ut < 8; ++ut) {
        f32x16 ca, cb;
        {
            const float* bp = budL + ut * 32 + hi * 16;
            f32x4 b0 = *(const f32x4*)(bp), b1 = *(const f32x4*)(bp + 4);
            f32x4 b2 = *(const f32x4*)(bp + 8), b3 = *(const f32x4*)(bp + 12);
            ca[0]=b0[0]; ca[1]=b0[1]; ca[2]=b0[2]; ca[3]=b0[3];
            ca[4]=b1[0]; ca[5]=b1[1]; ca[6]=b1[2]; ca[7]=b1[3];
            ca[8]=b2[0]; ca[9]=b2[1]; ca[10]=b2[2]; ca[11]=b2[3];
            ca[12]=b3[0]; ca[13]=b3[1]; ca[14]=b3[2]; ca[15]=b3[3];
#pragma unroll
            for (int i = 0; i < 16; ++i) cb[i] = 0.f;
        }
        const char* wb = lds + ((ut * 8) << 9) + (lane << 3);
        ca = __builtin_amdgcn_mfma_f32_32x32x16_fp8_fp8(*(const i64*)(wb + 0*512), x0, ca, 0,0,0);
        cb = __builtin_amdgcn_mfma_f32_32x32x16_fp8_fp8(*(const i64*)(wb + 1*512), x1, cb, 0,0,0);
        ca = __builtin_amdgcn_mfma_f32_32x32x16_fp8_fp8(*(const i64*)(wb + 2*512), x2, ca, 0,0,0);
        cb = __builtin_amdgcn_mfma_f32_32x32x16_fp8_fp8(*(const i64*)(wb + 3*512), x3, cb, 0,0,0);
        ca = __builtin_amdgcn_mfma_f32_32x32x16_fp8_fp8(*(const i64*)(wb + 4*512), x4, ca, 0,0,0);
        cb = __builtin_amdgcn_mfma_f32_32x32x16_fp8_fp8(*(const i64*)(wb + 5*512), x5, cb, 0,0,0);
        ca = __builtin_amdgcn_mfma_f32_32x32x16_fp8_fp8(*(const i64*)(wb + 6*512), x6, ca, 0,0,0);
        cb = __builtin_amdgcn_mfma_f32_32x32x16_fp8_fp8(*(const i64*)(wb + 7*512), x7, cb, 0,0,0);

        i64 dlo, dhi;
        {
            f32x16 c;
#pragma unroll
            for (int i = 0; i < 16; ++i) c[i] = fmaxf(ca[i] + cb[i], 0.f);
            int d0 = pk8<false>(c[0],  c[1],  0); d0 = pk8<true>(c[2],  c[3],  d0);
            int d1 = pk8<false>(c[4],  c[5],  0); d1 = pk8<true>(c[6],  c[7],  d1);
            int d2 = pk8<false>(c[8],  c[9],  0); d2 = pk8<true>(c[10], c[11], d2);
            int d3 = pk8<false>(c[12], c[13], 0); d3 = pk8<true>(c[14], c[15], d3);
            int2v s = __builtin_amdgcn_permlane32_swap(d0, d1, false, false);
            int2v t = __builtin_amdgcn_permlane32_swap(d2, d3, false, false);
            dlo = __builtin_bit_cast(i64, s);
            dhi = __builtin_bit_cast(i64, t);
        }

        const char* w2 = lds + 32768 + ((ut * 8) << 9) + (lane << 3);
        o0 = __builtin_amdgcn_mfma_f32_32x32x16_fp8_fp8(*(const i64*)(w2 + 0*512), dlo, o0, 0,0,0);
        o1 = __builtin_amdgcn_mfma_f32_32x32x16_fp8_fp8(*(const i64*)(w2 + 1*512), dlo, o1, 0,0,0);
        o2 = __builtin_amdgcn_mfma_f32_32x32x16_fp8_fp8(*(const i64*)(w2 + 2*512), dlo, o2, 0,0,0);
        o3 = __builtin_amdgcn_mfma_f32_32x32x16_fp8_fp8(*(const i64*)(w2 + 3*512), dlo, o3, 0,0,0);
        o0 = __builtin_amdgcn_mfma_f32_32x32x16_fp8_fp8(*(const i64*)(w2 + 4*512), dhi, o0, 0,0,0);
        o1 = __builtin_amdgcn_mfma_f32_32x32x16_fp8_fp8(*(const i64*)(w2 + 5*512), dhi, o1, 0,0,0);
        o2 = __builtin_amdgcn_mfma_f32_32x32x16_fp8_fp8(*(const i64*)(w2 + 6*512), dhi, o2, 0,0,0);
        o3 = __builtin_amdgcn_mfma_f32_32x32x16_fp8_fp8(*(const i64*)(w2 + 7*512), dhi, o3, 0,0,0);
    }

    // ---- fused loss epilogue (bo already inside o) ----
    const int t = t0 + m;
    const float sel = (t > 0) ? 1.f : 0.f;
    const float* trow = xsb + (size_t)((t > 0) ? t - 1 : 0) * 128;
    float lacc = 0.f;
#define EPI(OV, DT)                                                      \
    {   _Pragma("unroll")                                                \
        for (int q = 0; q < 4; ++q) {                                    \
            f32x4 tg = *(const f32x4*)(trow + (DT) * 32 + q * 8 + hi * 4); \
            _Pragma("unroll")                                            \
            for (int j = 0; j < 4; ++j) {                                \
                float diff = tg[j] - OV[q * 4 + j];                      \
                lacc += sel * diff * diff;                               \
            }                                                            \
        }                                                                \
    }
    EPI(o0, 0) EPI(o1, 1) EPI(o2, 2) EPI(o3, 3)
#undef EPI

    // ---- block reduction + last-block final (R18-verified pattern) ----
#pragma unroll
    for (int o = 32; o > 0; o >>= 1) lacc += __shfl_down(lacc, o);
    if (lane == 0) wsumf[wave] = lacc;
    __syncthreads();
    if (tid == 0) {
        float s = 0.f;
#pragma unroll
        for (int i = 0; i < 8; ++i) s += wsumf[i];
        part[bid] = s;
        __threadfence();
        int old = atomicAdd(cnt, 1);
        lflag[0] = (old == 1023) ? 1 : 0;
    }
    __syncthreads();
    if (lflag[0]) {
        __threadfence();
        float v = part[tid] + part[tid + 512];
        if (tid < 64) v += part2[tid];
#pragma unroll
        for (int o = 32; o > 0; o >>= 1) v += __shfl_down(v, o);
        if (lane == 0) wsumf[wave] = v;
        __syncthreads();
        if (tid == 0) {
            float s = 0.f;
#pragma unroll
            for (int i = 0; i < 8; ++i) s += wsumf[i];
            *loss = s * (1.f / 262144.f);
        }
    }
}

extern "C" void kernel_launch(void* const* d_in, const int* in_sizes, int n_in,
                              void* d_out, int out_size, void* d_ws, size_t ws_size,
                              hipStream_t stream) {
    const float* xs = (const float*)d_in[0];
    const float* We = (const float*)d_in[1];
    const float* be = (const float*)d_in[2];
    // d_in[3] = ue (unused: encoder hidden state is always zero)
    const float* Wd = (const float*)d_in[4];
    const float* bd = (const float*)d_in[5];
    const float* ud = (const float*)d_in[6];
    const float* Wo = (const float*)d_in[7];
    const float* bo = (const float*)d_in[8];
    float* loss = (float*)d_out;

    char* wsb = (char*)d_ws;
    float* budR  = (float*)(wsb);             // 65536 B
    char*  WF8   = (char*)(wsb + 65536);      // 65536 B
    float* boR   = (float*)(wsb + 131072);    // 512 B
    float* part  = (float*)(wsb + 131584);    // 4096 B (1024 block partials)
    float* part2 = (float*)(wsb + 135680);    // 256 B  (64 loss0 partials)
    int*   cnt   = (int*)(wsb + 135936);      // 4 B completion counter

    hipMemsetAsync(cnt, 0, 4, stream);
    k_pre<<<64, 256, 0, stream>>>(xs, We, be, Wd, bd, ud, Wo, bo,
                                  budR, boR, WF8, part2);
    k_main<<<1024, 512, 0, stream>>>(xs, budR, boR, WF8, part2, part, cnt, loss);
}

// Round 20
// 91.684 us; speedup vs baseline: 1.3163x; 1.0409x over previous
//
#include <hip/hip_runtime.h>

#define T_LEN 4096
#define D_IN 128
#define U_H 256
#define REC_MAXV 0.0625f

typedef __attribute__((ext_vector_type(4))) float f32x4;
typedef __attribute__((ext_vector_type(16))) float f32x16;
typedef __attribute__((ext_vector_type(2))) int int2v;
typedef long long i64;

template <bool HI>
__device__ __forceinline__ int pk8(float a, float b, int old) {
    return __builtin_amdgcn_cvt_pk_fp8_f32(a, b, old, HI);
}

__device__ __forceinline__ int reord32(int u) {
    int r = u & 31;
    return ((u >> 5) << 5) + (((r >> 2) & 1) << 4) + ((r >> 3) << 2) + (r & 3);
}

// -------- kernel 0 (fused prep): h, budR, boR, fp8 weight frags, loss0 -------
__global__ void k_pre(const float* __restrict__ xs, const float* __restrict__ We,
                      const float* __restrict__ be, const float* __restrict__ Wd,
                      const float* __restrict__ bd, const float* __restrict__ ud,
                      const float* __restrict__ Wo, const float* __restrict__ bo,
                      float* __restrict__ budR, float* __restrict__ boR,
                      char* __restrict__ WF8, float* __restrict__ part2) {
    __shared__ __align__(16) float hL[256];
    __shared__ float red[2];
    const int b = blockIdx.x, u = threadIdx.x;

    const f32x4* xr = (const f32x4*)(xs + ((size_t)b * T_LEN + (T_LEN - 1)) * D_IN);
    const f32x4* wr = (const f32x4*)(We + (size_t)u * D_IN);
    float s = 0.f;
#pragma unroll
    for (int i = 0; i < 32; ++i) {
        f32x4 a = xr[i], w = wr[i];
        s += a[0]*w[0] + a[1]*w[1] + a[2]*w[2] + a[3]*w[3];
    }
    s += be[u];
    s = fmaxf(s, 0.f);
    hL[u] = s;

    float udc = fminf(fmaxf(ud[u], -REC_MAXV), REC_MAXV);
    budR[(b << 8) + reord32(u)] = bd[u] + udc * s;

    if (b == 0 && u < 128) boR[reord32(u)] = bo[u];

    int gid = b * 256 + u;
    if (gid < 4096) {
        int f = gid >> 6, l = gid & 63;
        int ut = f >> 3, ks = f & 7;
        const float* src = Wd + (size_t)(ut * 32 + (l & 31)) * D_IN + ks * 16 + (l >> 5) * 8;
        int lo = pk8<false>(src[0], src[1], 0); lo = pk8<true>(src[2], src[3], lo);
        int hh = pk8<false>(src[4], src[5], 0); hh = pk8<true>(src[6], src[7], hh);
        *(int2v*)(WF8 + (size_t)gid * 8) = (int2v){lo, hh};
    } else if (gid < 8192) {
        int g = gid - 4096;
        int f = g >> 6, l = g & 63;
        int uk = f >> 2, dt = f & 3;
        const float* src = Wo + (size_t)(dt * 32 + (l & 31)) * U_H + uk * 16 + (l >> 5) * 8;
        int lo = pk8<false>(src[0], src[1], 0); lo = pk8<true>(src[2], src[3], lo);
        int hh = pk8<false>(src[4], src[5], 0); hh = pk8<true>(src[6], src[7], hh);
        *(int2v*)(WF8 + 32768 + (size_t)g * 8) = (int2v){lo, hh};
    }
    __syncthreads();

    float v = 0.f;
    if (u < 128) {
        const f32x4* hr = (const f32x4*)hL;
        const f32x4* wo = (const f32x4*)(Wo + (size_t)u * U_H);
        float s2 = 0.f;
#pragma unroll
        for (int i = 0; i < 64; ++i) {
            f32x4 a = hr[i], w = wo[i];
            s2 += a[0]*w[0] + a[1]*w[1] + a[2]*w[2] + a[3]*w[3];
        }
        s2 += bo[u];
        float x = xs[((size_t)b * T_LEN + T_LEN - 1) * D_IN + u];
        float diff = x - s2;
        v = diff * diff;
    }
#pragma unroll
    for (int o = 32; o > 0; o >>= 1) v += __shfl_down(v, o);
    if (u == 0) red[0] = v;
    if (u == 64) red[1] = v;
    __syncthreads();
    if (u == 0) part2[b] = red[0] + red[1];
}

// ---------------- kernel 1: main (EXACT R16 body) + last-block final ---------
// 1024 blocks x 512 threads (8 waves), 1 tile (32 rows)/wave. X loads AFTER
// the staging barrier (R16 order -- R19's early-load variant regressed 40%).
// Only change vs R16: final reduction folded in via last-block-done pattern.
__global__ __launch_bounds__(512, 2) void k_main(
        const float* __restrict__ xs, const float* __restrict__ budR,
        const float* __restrict__ boR, const char* __restrict__ WF8,
        const float* __restrict__ part2, float* __restrict__ part,
        int* __restrict__ cnt, float* __restrict__ loss) {
    __shared__ __align__(16) char lds[67200];
    const int tid = threadIdx.x;
    const int bid = blockIdx.x;

    for (int i = tid; i < 4096; i += 512)
        ((f32x4*)lds)[i] = ((const f32x4*)WF8)[i];
    const int b = bid >> 4;          // 16 blocks per batch-entry
    if (tid < 64) ((f32x4*)(lds + 65536))[tid] = ((const f32x4*)(budR + b * 256))[tid];
    else if (tid < 96) ((f32x4*)(lds + 66560))[tid - 64] = ((const f32x4*)boR)[tid - 64];
    __syncthreads();

    const int wave = tid >> 6, lane = tid & 63;
    const int m = lane & 31, hi = lane >> 5;
    const float* xsb = xs + ((size_t)b << 19);
    const float* budL = (const float*)(lds + 65536);
    const float* boL  = (const float*)(lds + 66560);
    float* wsumf = (float*)(lds + 67072);
    int*   lflag = (int*)(lds + 67104);

    const int tile = bid * 8 + wave;
    const int t0 = (tile & 127) << 5;

    // ---- X row -> fp8 B-frags (8 named i64) ----
    const float* xrow = xsb + (size_t)(t0 + m) * 128 + hi * 8;
    i64 x0, x1, x2, x3, x4, x5, x6, x7;
    {
#define LDX(KS, XV)                                                      \
        {   f32x4 v0 = *(const f32x4*)(xrow + KS * 16);                  \
            f32x4 v1 = *(const f32x4*)(xrow + KS * 16 + 4);              \
            int lo = pk8<false>(v0[0], v0[1], 0); lo = pk8<true>(v0[2], v0[3], lo); \
            int hh = pk8<false>(v1[0], v1[1], 0); hh = pk8<true>(v1[2], v1[3], hh); \
            XV = __builtin_bit_cast(i64, (int2v){lo, hh}); }
        LDX(0, x0) LDX(1, x1) LDX(2, x2) LDX(3, x3)
        LDX(4, x4) LDX(5, x5) LDX(6, x6) LDX(7, x7)
#undef LDX
    }

    // ---- o accumulators init from boR (bo folded into GEMM2 C-init) ----
    f32x16 o0, o1, o2, o3;
#define OINIT(OV, DT)                                                    \
    {   const float* bp = boL + (DT) * 32 + hi * 16;                     \
        f32x4 b0 = *(const f32x4*)(bp), b1 = *(const f32x4*)(bp + 4);    \
        f32x4 b2 = *(const f32x4*)(bp + 8), b3 = *(const f32x4*)(bp + 12); \
        OV[0]=b0[0]; OV[1]=b0[1]; OV[2]=b0[2]; OV[3]=b0[3];              \
        OV[4]=b1[0]; OV[5]=b1[1]; OV[6]=b1[2]; OV[7]=b1[3];              \
        OV[8]=b2[0]; OV[9]=b2[1]; OV[10]=b2[2]; OV[11]=b2[3];            \
        OV[12]=b3[0]; OV[13]=b3[1]; OV[14]=b3[2]; OV[15]=b3[3]; }
    OINIT(o0, 0) OINIT(o1, 1) OINIT(o2, 2) OINIT(o3, 3)
#undef OINIT

    // ---- main rolled loop over ut (I$-resident body) ----
#pragma clang loop unroll(disable)
    for (int ut = 0; ut < 8; ++ut) {
        f32x16 ca, cb;
        {
            const float* bp = budL + ut * 32 + hi * 16;
            f32x4 b0 = *(const f32x4*)(bp), b1 = *(const f32x4*)(bp + 4);
            f32x4 b2 = *(const f32x4*)(bp + 8), b3 = *(const f32x4*)(bp + 12);
            ca[0]=b0[0]; ca[1]=b0[1]; ca[2]=b0[2]; ca[3]=b0[3];
            ca[4]=b1[0]; ca[5]=b1[1]; ca[6]=b1[2]; ca[7]=b1[3];
            ca[8]=b2[0]; ca[9]=b2[1]; ca[10]=b2[2]; ca[11]=b2[3];
            ca[12]=b3[0]; ca[13]=b3[1]; ca[14]=b3[2]; ca[15]=b3[3];
#pragma unroll
            for (int i = 0; i < 16; ++i) cb[i] = 0.f;
        }
        const char* wb = lds + ((ut * 8) << 9) + (lane << 3);
        ca = __builtin_amdgcn_mfma_f32_32x32x16_fp8_fp8(*(const i64*)(wb + 0*512), x0, ca, 0,0,0);
        cb = __builtin_amdgcn_mfma_f32_32x32x16_fp8_fp8(*(const i64*)(wb + 1*512), x1, cb, 0,0,0);
        ca = __builtin_amdgcn_mfma_f32_32x32x16_fp8_fp8(*(const i64*)(wb + 2*512), x2, ca, 0,0,0);
        cb = __builtin_amdgcn_mfma_f32_32x32x16_fp8_fp8(*(const i64*)(wb + 3*512), x3, cb, 0,0,0);
        ca = __builtin_amdgcn_mfma_f32_32x32x16_fp8_fp8(*(const i64*)(wb + 4*512), x4, ca, 0,0,0);
        cb = __builtin_amdgcn_mfma_f32_32x32x16_fp8_fp8(*(const i64*)(wb + 5*512), x5, cb, 0,0,0);
        ca = __builtin_amdgcn_mfma_f32_32x32x16_fp8_fp8(*(const i64*)(wb + 6*512), x6, ca, 0,0,0);
        cb = __builtin_amdgcn_mfma_f32_32x32x16_fp8_fp8(*(const i64*)(wb + 7*512), x7, cb, 0,0,0);

        i64 dlo, dhi;
        {
            f32x16 c;
#pragma unroll
            for (int i = 0; i < 16; ++i) c[i] = fmaxf(ca[i] + cb[i], 0.f);
            int d0 = pk8<false>(c[0],  c[1],  0); d0 = pk8<true>(c[2],  c[3],  d0);
            int d1 = pk8<false>(c[4],  c[5],  0); d1 = pk8<true>(c[6],  c[7],  d1);
            int d2 = pk8<false>(c[8],  c[9],  0); d2 = pk8<true>(c[10], c[11], d2);
            int d3 = pk8<false>(c[12], c[13], 0); d3 = pk8<true>(c[14], c[15], d3);
            int2v s = __builtin_amdgcn_permlane32_swap(d0, d1, false, false);
            int2v t = __builtin_amdgcn_permlane32_swap(d2, d3, false, false);
            dlo = __builtin_bit_cast(i64, s);
            dhi = __builtin_bit_cast(i64, t);
        }

        const char* w2 = lds + 32768 + ((ut * 8) << 9) + (lane << 3);
        o0 = __builtin_amdgcn_mfma_f32_32x32x16_fp8_fp8(*(const i64*)(w2 + 0*512), dlo, o0, 0,0,0);
        o1 = __builtin_amdgcn_mfma_f32_32x32x16_fp8_fp8(*(const i64*)(w2 + 1*512), dlo, o1, 0,0,0);
        o2 = __builtin_amdgcn_mfma_f32_32x32x16_fp8_fp8(*(const i64*)(w2 + 2*512), dlo, o2, 0,0,0);
        o3 = __builtin_amdgcn_mfma_f32_32x32x16_fp8_fp8(*(const i64*)(w2 + 3*512), dlo, o3, 0,0,0);
        o0 = __builtin_amdgcn_mfma_f32_32x32x16_fp8_fp8(*(const i64*)(w2 + 4*512), dhi, o0, 0,0,0);
        o1 = __builtin_amdgcn_mfma_f32_32x32x16_fp8_fp8(*(const i64*)(w2 + 5*512), dhi, o1, 0,0,0);
        o2 = __builtin_amdgcn_mfma_f32_32x32x16_fp8_fp8(*(const i64*)(w2 + 6*512), dhi, o2, 0,0,0);
        o3 = __builtin_amdgcn_mfma_f32_32x32x16_fp8_fp8(*(const i64*)(w2 + 7*512), dhi, o3, 0,0,0);
    }

    // ---- fused loss epilogue (bo already inside o) ----
    const int t = t0 + m;
    const float sel = (t > 0) ? 1.f : 0.f;
    const float* trow = xsb + (size_t)((t > 0) ? t - 1 : 0) * 128;
    float lacc = 0.f;
#define EPI(OV, DT)                                                      \
    {   _Pragma("unroll")                                                \
        for (int q = 0; q < 4; ++q) {                                    \
            f32x4 tg = *(const f32x4*)(trow + (DT) * 32 + q * 8 + hi * 4); \
            _Pragma("unroll")                                            \
            for (int j = 0; j < 4; ++j) {                                \
                float diff = tg[j] - OV[q * 4 + j];                      \
                lacc += sel * diff * diff;                               \
            }                                                            \
        }                                                                \
    }
    EPI(o0, 0) EPI(o1, 1) EPI(o2, 2) EPI(o3, 3)
#undef EPI

    // ---- block reduction + last-block final ----
#pragma unroll
    for (int o = 32; o > 0; o >>= 1) lacc += __shfl_down(lacc, o);
    if (lane == 0) wsumf[wave] = lacc;
    __syncthreads();
    if (tid == 0) {
        float s = 0.f;
#pragma unroll
        for (int i = 0; i < 8; ++i) s += wsumf[i];
        part[bid] = s;
        __threadfence();
        int old = atomicAdd(cnt, 1);
        lflag[0] = (old == 1023) ? 1 : 0;
    }
    __syncthreads();
    if (lflag[0]) {
        __threadfence();
        float v = part[tid] + part[tid + 512];
        if (tid < 64) v += part2[tid];
#pragma unroll
        for (int o = 32; o > 0; o >>= 1) v += __shfl_down(v, o);
        if (lane == 0) wsumf[wave] = v;
        __syncthreads();
        if (tid == 0) {
            float s = 0.f;
#pragma unroll
            for (int i = 0; i < 8; ++i) s += wsumf[i];
            *loss = s * (1.f / 262144.f);
        }
    }
}

extern "C" void kernel_launch(void* const* d_in, const int* in_sizes, int n_in,
                              void* d_out, int out_size, void* d_ws, size_t ws_size,
                              hipStream_t stream) {
    const float* xs = (const float*)d_in[0];
    const float* We = (const float*)d_in[1];
    const float* be = (const float*)d_in[2];
    // d_in[3] = ue (unused: encoder hidden state is always zero)
    const float* Wd = (const float*)d_in[4];
    const float* bd = (const float*)d_in[5];
    const float* ud = (const float*)d_in[6];
    const float* Wo = (const float*)d_in[7];
    const float* bo = (const float*)d_in[8];
    float* loss = (float*)d_out;

    char* wsb = (char*)d_ws;
    float* budR  = (float*)(wsb);             // 65536 B
    char*  WF8   = (char*)(wsb + 65536);      // 65536 B
    float* boR   = (float*)(wsb + 131072);    // 512 B
    float* part  = (float*)(wsb + 131584);    // 4096 B (1024 block partials)
    float* part2 = (float*)(wsb + 135680);    // 256 B  (64 loss0 partials)
    int*   cnt   = (int*)(wsb + 135936);      // 4 B completion counter

    hipMemsetAsync(cnt, 0, 4, stream);
    k_pre<<<64, 256, 0, stream>>>(xs, We, be, Wd, bd, ud, Wo, bo,
                                  budR, boR, WF8, part2);
    k_main<<<1024, 512, 0, stream>>>(xs, budR, boR, WF8, part2, part, cnt, loss);
}

// Round 21
// 59.951 us; speedup vs baseline: 2.0130x; 1.5293x over previous
//
#include <hip/hip_runtime.h>

#define T_LEN 4096
#define D_IN 128
#define U_H 256
#define REC_MAXV 0.0625f

typedef __attribute__((ext_vector_type(4))) float f32x4;
typedef __attribute__((ext_vector_type(16))) float f32x16;
typedef __attribute__((ext_vector_type(2))) int int2v;
typedef long long i64;

template <bool HI>
__device__ __forceinline__ int pk8(float a, float b, int old) {
    return __builtin_amdgcn_cvt_pk_fp8_f32(a, b, old, HI);
}

__device__ __forceinline__ int reord32(int u) {
    int r = u & 31;
    return ((u >> 5) << 5) + (((r >> 2) & 1) << 4) + ((r >> 3) << 2) + (r & 3);
}

// -------- kernel 0 (fused prep): h, budR, boR, fp8 weight frags, loss0 -------
__global__ void k_pre(const float* __restrict__ xs, const float* __restrict__ We,
                      const float* __restrict__ be, const float* __restrict__ Wd,
                      const float* __restrict__ bd, const float* __restrict__ ud,
                      const float* __restrict__ Wo, const float* __restrict__ bo,
                      float* __restrict__ budR, float* __restrict__ boR,
                      char* __restrict__ WF8, float* __restrict__ part2) {
    __shared__ __align__(16) float hL[256];
    __shared__ float red[2];
    const int b = blockIdx.x, u = threadIdx.x;

    const f32x4* xr = (const f32x4*)(xs + ((size_t)b * T_LEN + (T_LEN - 1)) * D_IN);
    const f32x4* wr = (const f32x4*)(We + (size_t)u * D_IN);
    float s = 0.f;
#pragma unroll
    for (int i = 0; i < 32; ++i) {
        f32x4 a = xr[i], w = wr[i];
        s += a[0]*w[0] + a[1]*w[1] + a[2]*w[2] + a[3]*w[3];
    }
    s += be[u];
    s = fmaxf(s, 0.f);
    hL[u] = s;

    float udc = fminf(fmaxf(ud[u], -REC_MAXV), REC_MAXV);
    budR[(b << 8) + reord32(u)] = bd[u] + udc * s;

    if (b == 0 && u < 128) boR[reord32(u)] = bo[u];

    int gid = b * 256 + u;
    if (gid < 4096) {
        int f = gid >> 6, l = gid & 63;
        int ut = f >> 3, ks = f & 7;
        const float* src = Wd + (size_t)(ut * 32 + (l & 31)) * D_IN + ks * 16 + (l >> 5) * 8;
        int lo = pk8<false>(src[0], src[1], 0); lo = pk8<true>(src[2], src[3], lo);
        int hh = pk8<false>(src[4], src[5], 0); hh = pk8<true>(src[6], src[7], hh);
        *(int2v*)(WF8 + (size_t)gid * 8) = (int2v){lo, hh};
    } else if (gid < 8192) {
        int g = gid - 4096;
        int f = g >> 6, l = g & 63;
        int uk = f >> 2, dt = f & 3;
        const float* src = Wo + (size_t)(dt * 32 + (l & 31)) * U_H + uk * 16 + (l >> 5) * 8;
        int lo = pk8<false>(src[0], src[1], 0); lo = pk8<true>(src[2], src[3], lo);
        int hh = pk8<false>(src[4], src[5], 0); hh = pk8<true>(src[6], src[7], hh);
        *(int2v*)(WF8 + 32768 + (size_t)g * 8) = (int2v){lo, hh};
    }
    __syncthreads();

    float v = 0.f;
    if (u < 128) {
        const f32x4* hr = (const f32x4*)hL;
        const f32x4* wo = (const f32x4*)(Wo + (size_t)u * U_H);
        float s2 = 0.f;
#pragma unroll
        for (int i = 0; i < 64; ++i) {
            f32x4 a = hr[i], w = wo[i];
            s2 += a[0]*w[0] + a[1]*w[1] + a[2]*w[2] + a[3]*w[3];
        }
        s2 += bo[u];
        float x = xs[((size_t)b * T_LEN + T_LEN - 1) * D_IN + u];
        float diff = x - s2;
        v = diff * diff;
    }
#pragma unroll
    for (int o = 32; o > 0; o >>= 1) v += __shfl_down(v, o);
    if (u == 0) red[0] = v;
    if (u == 64) red[1] = v;
    __syncthreads();
    if (u == 0) part2[b] = red[0] + red[1];
}

// ---------------- kernel 1: main pipeline -- ROLLED ut-loop (R16 exact) ------
// 1024 blocks x 512 threads (8 waves), 1 tile (32 rows) per wave, M=32.
// Rolled ut-loop keeps the hot body I$-resident (~120 instrs) -- the one
// structural change that measurably beat the unrolled one-shot body (R16:
// 63.7 -> 60.3us). All later variants (cooperative fusion, in-block prep,
// early X loads, last-block final) regressed; this is the measured optimum.
__global__ __launch_bounds__(512, 2) void k_main(
        const float* __restrict__ xs, const float* __restrict__ budR,
        const float* __restrict__ boR, const char* __restrict__ WF8,
        float* __restrict__ part) {
    __shared__ __align__(16) char lds[67200];
    const int tid = threadIdx.x;

    for (int i = tid; i < 4096; i += 512)
        ((f32x4*)lds)[i] = ((const f32x4*)WF8)[i];
    const int b = blockIdx.x >> 4;          // 16 blocks per batch-entry
    if (tid < 64) ((f32x4*)(lds + 65536))[tid] = ((const f32x4*)(budR + b * 256))[tid];
    else if (tid < 96) ((f32x4*)(lds + 66560))[tid - 64] = ((const f32x4*)boR)[tid - 64];
    __syncthreads();

    const int wave = tid >> 6, lane = tid & 63;
    const int m = lane & 31, hi = lane >> 5;
    const float* xsb = xs + ((size_t)b << 19);
    const float* budL = (const float*)(lds + 65536);
    const float* boL  = (const float*)(lds + 66560);
    float* wsumf = (float*)(lds + 67072);

    const int tile = blockIdx.x * 8 + wave;
    const int t0 = (tile & 127) << 5;

    // ---- X row -> fp8 B-frags (8 named i64) ----
    const float* xrow = xsb + (size_t)(t0 + m) * 128 + hi * 8;
    i64 x0, x1, x2, x3, x4, x5, x6, x7;
    {
#define LDX(KS, XV)                                                      \
        {   f32x4 v0 = *(const f32x4*)(xrow + KS * 16);                  \
            f32x4 v1 = *(const f32x4*)(xrow + KS * 16 + 4);              \
            int lo = pk8<false>(v0[0], v0[1], 0); lo = pk8<true>(v0[2], v0[3], lo); \
            int hh = pk8<false>(v1[0], v1[1], 0); hh = pk8<true>(v1[2], v1[3], hh); \
            XV = __builtin_bit_cast(i64, (int2v){lo, hh}); }
        LDX(0, x0) LDX(1, x1) LDX(2, x2) LDX(3, x3)
        LDX(4, x4) LDX(5, x5) LDX(6, x6) LDX(7, x7)
#undef LDX
    }

    // ---- o accumulators init from boR (bo folded into GEMM2 C-init) ----
    f32x16 o0, o1, o2, o3;
#define OINIT(OV, DT)                                                    \
    {   const float* bp = boL + (DT) * 32 + hi * 16;                     \
        f32x4 b0 = *(const f32x4*)(bp), b1 = *(const f32x4*)(bp + 4);    \
        f32x4 b2 = *(const f32x4*)(bp + 8), b3 = *(const f32x4*)(bp + 12); \
        OV[0]=b0[0]; OV[1]=b0[1]; OV[2]=b0[2]; OV[3]=b0[3];              \
        OV[4]=b1[0]; OV[5]=b1[1]; OV[6]=b1[2]; OV[7]=b1[3];              \
        OV[8]=b2[0]; OV[9]=b2[1]; OV[10]=b2[2]; OV[11]=b2[3];            \
        OV[12]=b3[0]; OV[13]=b3[1]; OV[14]=b3[2]; OV[15]=b3[3]; }
    OINIT(o0, 0) OINIT(o1, 1) OINIT(o2, 2) OINIT(o3, 3)
#undef OINIT

    // ---- main rolled loop over ut ----
#pragma clang loop unroll(disable)
    for (int ut = 0; ut < 8; ++ut) {
        // ph1: C-init ca from budR (bias folded), cb = 0
        f32x16 ca, cb;
        {
            const float* bp = budL + ut * 32 + hi * 16;
            f32x4 b0 = *(const f32x4*)(bp), b1 = *(const f32x4*)(bp + 4);
            f32x4 b2 = *(const f32x4*)(bp + 8), b3 = *(const f32x4*)(bp + 12);
            ca[0]=b0[0]; ca[1]=b0[1]; ca[2]=b0[2]; ca[3]=b0[3];
            ca[4]=b1[0]; ca[5]=b1[1]; ca[6]=b1[2]; ca[7]=b1[3];
            ca[8]=b2[0]; ca[9]=b2[1]; ca[10]=b2[2]; ca[11]=b2[3];
            ca[12]=b3[0]; ca[13]=b3[1]; ca[14]=b3[2]; ca[15]=b3[3];
#pragma unroll
            for (int i = 0; i < 16; ++i) cb[i] = 0.f;
        }
        const char* wb = lds + ((ut * 8) << 9) + (lane << 3);
        ca = __builtin_amdgcn_mfma_f32_32x32x16_fp8_fp8(*(const i64*)(wb + 0*512), x0, ca, 0,0,0);
        cb = __builtin_amdgcn_mfma_f32_32x32x16_fp8_fp8(*(const i64*)(wb + 1*512), x1, cb, 0,0,0);
        ca = __builtin_amdgcn_mfma_f32_32x32x16_fp8_fp8(*(const i64*)(wb + 2*512), x2, ca, 0,0,0);
        cb = __builtin_amdgcn_mfma_f32_32x32x16_fp8_fp8(*(const i64*)(wb + 3*512), x3, cb, 0,0,0);
        ca = __builtin_amdgcn_mfma_f32_32x32x16_fp8_fp8(*(const i64*)(wb + 4*512), x4, ca, 0,0,0);
        cb = __builtin_amdgcn_mfma_f32_32x32x16_fp8_fp8(*(const i64*)(wb + 5*512), x5, cb, 0,0,0);
        ca = __builtin_amdgcn_mfma_f32_32x32x16_fp8_fp8(*(const i64*)(wb + 6*512), x6, ca, 0,0,0);
        cb = __builtin_amdgcn_mfma_f32_32x32x16_fp8_fp8(*(const i64*)(wb + 7*512), x7, cb, 0,0,0);

        // relu + fp8 pack + permlane32_swap -> dec frags for uk=2ut, 2ut+1
        i64 dlo, dhi;
        {
            f32x16 c;
#pragma unroll
            for (int i = 0; i < 16; ++i) c[i] = fmaxf(ca[i] + cb[i], 0.f);
            int d0 = pk8<false>(c[0],  c[1],  0); d0 = pk8<true>(c[2],  c[3],  d0);
            int d1 = pk8<false>(c[4],  c[5],  0); d1 = pk8<true>(c[6],  c[7],  d1);
            int d2 = pk8<false>(c[8],  c[9],  0); d2 = pk8<true>(c[10], c[11], d2);
            int d3 = pk8<false>(c[12], c[13], 0); d3 = pk8<true>(c[14], c[15], d3);
            int2v s = __builtin_amdgcn_permlane32_swap(d0, d1, false, false);
            int2v t = __builtin_amdgcn_permlane32_swap(d2, d3, false, false);
            dlo = __builtin_bit_cast(i64, s);
            dhi = __builtin_bit_cast(i64, t);
        }

        // ph2: weights for uk=2ut (dlo) and uk=2ut+1 (dhi), 4 dt each
        const char* w2 = lds + 32768 + ((ut * 8) << 9) + (lane << 3);
        o0 = __builtin_amdgcn_mfma_f32_32x32x16_fp8_fp8(*(const i64*)(w2 + 0*512), dlo, o0, 0,0,0);
        o1 = __builtin_amdgcn_mfma_f32_32x32x16_fp8_fp8(*(const i64*)(w2 + 1*512), dlo, o1, 0,0,0);
        o2 = __builtin_amdgcn_mfma_f32_32x32x16_fp8_fp8(*(const i64*)(w2 + 2*512), dlo, o2, 0,0,0);
        o3 = __builtin_amdgcn_mfma_f32_32x32x16_fp8_fp8(*(const i64*)(w2 + 3*512), dlo, o3, 0,0,0);
        o0 = __builtin_amdgcn_mfma_f32_32x32x16_fp8_fp8(*(const i64*)(w2 + 4*512), dhi, o0, 0,0,0);
        o1 = __builtin_amdgcn_mfma_f32_32x32x16_fp8_fp8(*(const i64*)(w2 + 5*512), dhi, o1, 0,0,0);
        o2 = __builtin_amdgcn_mfma_f32_32x32x16_fp8_fp8(*(const i64*)(w2 + 6*512), dhi, o2, 0,0,0);
        o3 = __builtin_amdgcn_mfma_f32_32x32x16_fp8_fp8(*(const i64*)(w2 + 7*512), dhi, o3, 0,0,0);
    }

    // ---- fused loss epilogue (bo already inside o) ----
    const int t = t0 + m;
    const float sel = (t > 0) ? 1.f : 0.f;
    const float* trow = xsb + (size_t)((t > 0) ? t - 1 : 0) * 128;
    float lacc = 0.f;
#define EPI(OV, DT)                                                      \
    {   _Pragma("unroll")                                                \
        for (int q = 0; q < 4; ++q) {                                    \
            f32x4 tg = *(const f32x4*)(trow + (DT) * 32 + q * 8 + hi * 4); \
            _Pragma("unroll")                                            \
            for (int j = 0; j < 4; ++j) {                                \
                float diff = tg[j] - OV[q * 4 + j];                      \
                lacc += sel * diff * diff;                               \
            }                                                            \
        }                                                                \
    }
    EPI(o0, 0) EPI(o1, 1) EPI(o2, 2) EPI(o3, 3)
#undef EPI

    // ---- block-level reduction: ONE store per block, no atomic ----
#pragma unroll
    for (int o = 32; o > 0; o >>= 1) lacc += __shfl_down(lacc, o);
    if (lane == 0) wsumf[wave] = lacc;
    __syncthreads();
    if (tid == 0) {
        float s = 0.f;
#pragma unroll
        for (int i = 0; i < 8; ++i) s += wsumf[i];
        part[blockIdx.x] = s;
    }
}

// ---------------- kernel 2: final reduction (plain store, no atomic) ---------
__global__ void k_final(const float* __restrict__ part, const float* __restrict__ part2,
                        float* __restrict__ loss) {
    __shared__ float ws[16];
    const int tid = threadIdx.x;   // 1024
    float v = part[tid];
    if (tid < 64) v += part2[tid];
#pragma unroll
    for (int o = 32; o > 0; o >>= 1) v += __shfl_down(v, o);
    if ((tid & 63) == 0) ws[tid >> 6] = v;
    __syncthreads();
    if (tid == 0) {
        float s = 0.f;
#pragma unroll
        for (int i = 0; i < 16; ++i) s += ws[i];
        *loss = s * (1.f / 262144.f);
    }
}

extern "C" void kernel_launch(void* const* d_in, const int* in_sizes, int n_in,
                              void* d_out, int out_size, void* d_ws, size_t ws_size,
                              hipStream_t stream) {
    const float* xs = (const float*)d_in[0];
    const float* We = (const float*)d_in[1];
    const float* be = (const float*)d_in[2];
    // d_in[3] = ue (unused: encoder hidden state is always zero)
    const float* Wd = (const float*)d_in[4];
    const float* bd = (const float*)d_in[5];
    const float* ud = (const float*)d_in[6];
    const float* Wo = (const float*)d_in[7];
    const float* bo = (const float*)d_in[8];
    float* loss = (float*)d_out;

    char* ws = (char*)d_ws;
    float* budR  = (float*)(ws);             // 65536 B
    char*  WF8   = (char*)(ws + 65536);      // 65536 B
    float* boR   = (float*)(ws + 131072);    // 512 B
    float* part  = (float*)(ws + 131584);    // 4096 B (1024 block partials)
    float* part2 = (float*)(ws + 135680);    // 256 B  (64 loss0 partials)

    k_pre<<<64, 256, 0, stream>>>(xs, We, be, Wd, bd, ud, Wo, bo,
                                  budR, boR, WF8, part2);
    k_main<<<1024, 512, 0, stream>>>(xs, budR, boR, WF8, part);
    k_final<<<1, 1024, 0, stream>>>(part, part2, loss);
}